// Round 1
// 115.654 us; speedup vs baseline: 1.0083x; 1.0083x over previous
//
#include <hip/hip_runtime.h>
#include <hip/hip_bf16.h>

#define N_NODES 50000
#define N_EDGES 800000
#define FEAT 64
#define RANGE 32        // nodes per K2 block
#define NBINS 1563      // ceil(50000/32)
#define K1B 250         // bin blocks; EPB = 3200 (multiple of 4)
#define EPB (N_EDGES / K1B)
#define SUB 16          // slots per (range, bin-block) chunk = one 64B line; fill ~ Poisson(2.05)
#define RSTRIDE 4096    // ent ints per range: 256 padded chunks x 16 (guard-free prefetch)
#define CAPP 48         // per-node bucket capacity (deg ~ Poisson(16); P(>48) ~ 1e-11)
#define BSTRIDE 52      // bucket row stride in ints (16B-aligned, odd bank step)
#define DUMMY N_NODES   // zero row index for degree padding
#define CONVB 391       // ceil((N_NODES+1)*FEAT/8 / 1024) conv blocks in fused K01

static __device__ __forceinline__ unsigned short f2bu(float f) {
    __hip_bfloat16 h = __float2bfloat16(f);
    return __builtin_bit_cast(unsigned short, h);
}

// K01: fused conv + bin. Conv (fp32->bf16 copy + zero dummy row) is pure-BW
// (~19 MB); bin is latency-bound (scattered 4B ent stores + LDS atomics).
// R11 theory: old bin ran 250x256 = 1 wave/SIMD — minimum occupancy, every
// scattered-store and atomic latency exposed. Fused grid: 1024-thread blocks,
// bin part is a SINGLE pass (800 threads x 4 edges = EPB exactly), 16 waves/CU,
// and conv overlaps bin instead of serializing in front of it.
__global__ __launch_bounds__(1024) void conv_bin_kernel(
    const float* __restrict__ src_feat,
    unsigned short* __restrict__ src16,
    const int* __restrict__ edge_src,
    const int* __restrict__ edge_dst,
    int* __restrict__ counts,       // [K1B][NBINS]  (b-major: sequential publish)
    int* __restrict__ ent)          // [NBINS][RSTRIDE] ; chunk (r,b) at r*4096+b*16
{
    __shared__ int h[NBINS];        // 6.25 KB cursors (bin blocks only)
    int tid = threadIdx.x;

    if (blockIdx.x < CONVB) {
        // ---- conv part: 8 floats -> 8 bf16 per thread ----
        int base = (blockIdx.x * 1024 + tid) * 8;
        if (base >= (N_NODES + 1) * FEAT) return;
        uint4 o;
        if (base < N_NODES * FEAT) {
            float4 a = *(const float4*)(src_feat + base);
            float4 b = *(const float4*)(src_feat + base + 4);
            o.x = (unsigned)f2bu(a.x) | ((unsigned)f2bu(a.y) << 16);
            o.y = (unsigned)f2bu(a.z) | ((unsigned)f2bu(a.w) << 16);
            o.z = (unsigned)f2bu(b.x) | ((unsigned)f2bu(b.y) << 16);
            o.w = (unsigned)f2bu(b.z) | ((unsigned)f2bu(b.w) << 16);
        } else {
            o = make_uint4(0, 0, 0, 0);
        }
        *(uint4*)(src16 + base) = o;
        return;
    }

    // ---- bin part: deterministic single-pass binning (round-10 lesson:
    // pos = atomicAdd gives the slot directly; counts published after). ----
    int b = blockIdx.x - CONVB;
    for (int r = tid; r < NBINS; r += 1024) h[r] = 0;
    __syncthreads();

    if (tid < EPB / 4) {            // exactly 800 threads, one int4 each
        int e = b * EPB + tid * 4;
        int4 s4 = *(const int4*)(edge_src + e);
        int4 d4 = *(const int4*)(edge_dst + e);
        int r0 = d4.x >> 5, r1 = d4.y >> 5, r2 = d4.z >> 5, r3 = d4.w >> 5;
        int p0 = atomicAdd(&h[r0], 1);
        int p1 = atomicAdd(&h[r1], 1);
        int p2 = atomicAdd(&h[r2], 1);
        int p3 = atomicAdd(&h[r3], 1);
        if (p0 < SUB) ent[r0 * RSTRIDE + b * SUB + p0] = ((d4.x & 31) << 16) | s4.x;
        if (p1 < SUB) ent[r1 * RSTRIDE + b * SUB + p1] = ((d4.y & 31) << 16) | s4.y;
        if (p2 < SUB) ent[r2 * RSTRIDE + b * SUB + p2] = ((d4.z & 31) << 16) | s4.z;
        if (p3 < SUB) ent[r3 * RSTRIDE + b * SUB + p3] = ((d4.w & 31) << 16) | s4.w;
    }
    __syncthreads();

    // Publish counts: contiguous 6.25 KB sequential write per block.
    for (int r = tid; r < NBINS; r += 1024) {
        int c = h[r];
        counts[b * NBINS + r] = (c > SUB) ? SUB : c;
    }
}

// Phase-B pipeline macros — all array indices compile-time (rule #20).
#define RDIDX(ID, Q)                                                          \
    _Pragma("unroll")                                                         \
    for (int m_ = 0; m_ < 4; ++m_) {                                          \
        int raw_ = bucket_w[(wave * 4 + m_) * BSTRIDE + (Q) * 4 + sub];       \
        ID[m_] = ((Q) < rows4[m_]) ? raw_ : DUMMY;                            \
    }
#define GLOAD(L, ID)                                                          \
    _Pragma("unroll")                                                         \
    for (int m_ = 0; m_ < 4; ++m_)                                            \
        L[m_] = *(const uint2*)(src16 + (size_t)ID[m_] * FEAT + fc * 4);
#define ACCUM(L)                                                              \
    _Pragma("unroll")                                                         \
    for (int m_ = 0; m_ < 4; ++m_) {                                          \
        acc[m_][0] += __uint_as_float(L[m_].x << 16);                         \
        acc[m_][1] += __uint_as_float(L[m_].x & 0xFFFF0000u);                 \
        acc[m_][2] += __uint_as_float(L[m_].y << 16);                         \
        acc[m_][3] += __uint_as_float(L[m_].y & 0xFFFF0000u);                 \
    }

// K2: guard-free unconditional ent prefetch -> LDS fine-sort (int cursors,
// no fp32 LDS atomics) -> 4-rows-per-load gather with register accumulation,
// now SOFTWARE-PIPELINED 2-deep (R11: per-iteration ds_read->lgkm->gather->
// vmcnt(0)->FMA chain exposed ~600cy vs ~32cy of VALU; loads for q+1 now
// issue before q's accumulate waits) -> butterfly reduce -> fused 8x8x8
// matmul. launch_bounds (512,6): headroom for the +~16 pipeline VGPRs so
// nothing spills; actual occupancy still derives from real VGPR use.
__global__ __launch_bounds__(512, 6) void sort_gather_mm_kernel(
    const unsigned short* __restrict__ src16,
    const float* __restrict__ dst_feat,
    const int* __restrict__ counts,
    const int* __restrict__ ent,
    float* __restrict__ out)
{
    __shared__ int bucket_w[RANGE * BSTRIDE];   // 6656 B
    __shared__ int cnt_s[256];                  // 250 real + 6 zero pads
    __shared__ int c[RANGE];

    int r = blockIdx.x;
    int tid = threadIdx.x;
    int wave = tid >> 6;
    int lane = tid & 63;

    // Unconditional ent prefetch: 8 coalesced ints per thread, issued FIRST
    // (no dependence on counts -> overlaps the counts/dst latency).
    const int* er = ent + (size_t)r * RSTRIDE;
    int ew[8];
    #pragma unroll
    for (int k = 0; k < 8; ++k)
        ew[k] = er[tid + k * 512];

    // Scattered counts reads ([b][r] layout), one per bin-block.
    if (tid < 256) cnt_s[tid] = (tid < K1B) ? counts[tid * NBINS + r] : 0;
    if (tid < RANGE) c[tid] = 0;

    // dst rows: consumed only in the epilogue (latency free).
    float Bv[4];
    #pragma unroll
    for (int m = 0; m < 4; ++m) {
        int n = r * RANGE + wave * 4 + m;
        Bv[m] = (n < N_NODES) ? dst_feat[n * FEAT + lane] : 0.f;
    }
    __syncthreads();

    // Phase A: filter prefetched slots, sort into per-node u32 buckets.
    #pragma unroll
    for (int k = 0; k < 8; ++k) {
        int g = tid + k * 512;
        int bb = g >> 4;              // SUB == 16
        int s  = g & 15;
        if (s < cnt_s[bb]) {
            int p = ew[k];
            int dl = p >> 16;
            int pos = atomicAdd(&c[dl], 1);
            if (pos < CAPP) bucket_w[dl * BSTRIDE + pos] = p & 0xFFFF;
        }
    }
    __syncthreads();

    // Pad each node's count to a multiple of 4 with the zero dummy row.
    if (tid < RANGE) {
        int cc = c[tid]; if (cc > CAPP) cc = CAPP;
        while (cc & 3) bucket_w[tid * BSTRIDE + cc++] = DUMMY;
        c[tid] = cc >> 2;             // rows-of-4 count
    }
    __syncthreads();

    // Phase B: wide gather, 2-deep pipelined. Lane covers row-slot (lane>>4),
    // features (lane&15)*4. One dwordx2 load = 4 rows x 128B per wave-instr.
    int sub = lane >> 4;
    int fc  = lane & 15;
    int rows4[4], qmax = 0;
    #pragma unroll
    for (int m = 0; m < 4; ++m) {
        rows4[m] = c[wave * 4 + m];
        qmax = (rows4[m] > qmax) ? rows4[m] : qmax;
    }

    float acc[4][4] = {{0.f,0.f,0.f,0.f},{0.f,0.f,0.f,0.f},
                       {0.f,0.f,0.f,0.f},{0.f,0.f,0.f,0.f}};
    {
        int idA[4], idB[4];
        uint2 LA[4], LB[4];
        if (qmax > 0) { RDIDX(idA, 0); GLOAD(LA, idA); }
        int q = 0;
        while (q < qmax) {           // qmax wave-uniform -> no divergence
            int qn = q + 1;
            if (qn < qmax) { RDIDX(idB, qn); GLOAD(LB, idB); }
            ACCUM(LA);
            q = qn;
            if (q >= qmax) break;
            qn = q + 1;
            if (qn < qmax) { RDIDX(idA, qn); GLOAD(LA, idA); }
            ACCUM(LB);
            q = qn;
        }
    }

    // Butterfly-reduce the 4 row-slots: all lanes end with full sums for
    // features fc*4+u of node m.
    #pragma unroll
    for (int m = 0; m < 4; ++m) {
        #pragma unroll
        for (int u = 0; u < 4; ++u) {
            acc[m][u] += __shfl_xor(acc[m][u], 16, 64);
            acc[m][u] += __shfl_xor(acc[m][u], 32, 64);
        }
    }

    // Epilogue: 8x8 matmul. S feature 8i+p lives in lane 2i+(p>>2), reg p&3.
    int i = lane >> 3;
    int j = lane & 7;
    #pragma unroll
    for (int m = 0; m < 4; ++m) {
        int n = r * RANGE + wave * 4 + m;
        if (n >= N_NODES) break;
        float res = 0.0f;
        #pragma unroll
        for (int p = 0; p < 8; ++p) {
            float s_ip = __shfl(acc[m][p & 3], 2 * i + (p >> 2), 64);
            float b_pj = __shfl(Bv[m], p * 8 + j, 64);
            res += s_ip * b_pj;
        }
        out[n * FEAT + lane] = res * 0.35355339059327373f;  // 1/sqrt(8)
    }
}

extern "C" void kernel_launch(void* const* d_in, const int* in_sizes, int n_in,
                              void* d_out, int out_size, void* d_ws, size_t ws_size,
                              hipStream_t stream) {
    const float* src_feat = (const float*)d_in[0];
    const float* dst_feat = (const float*)d_in[1];
    const int* edge_src = (const int*)d_in[2];
    const int* edge_dst = (const int*)d_in[3];
    float* out = (float*)d_out;

    // ws layout: counts [K1B][NBINS] 1,563,000 B (pad to 1,563,008)
    //            ent    [NBINS][RSTRIDE] ints = 25,608,192 B
    //            src16  (N_NODES+1)*FEAT u16  =  6,400,128 B   (~33.6 MB)
    char* w = (char*)d_ws;
    int* counts = (int*)w;                        w += 1563008;
    int* ent = (int*)w;                           w += (size_t)NBINS * RSTRIDE * 4;
    unsigned short* src16 = (unsigned short*)w;

    // Fused conv+bin: 391 conv blocks + 250 bin blocks, 1024 threads each.
    conv_bin_kernel<<<CONVB + K1B, 1024, 0, stream>>>(
        src_feat, src16, edge_src, edge_dst, counts, ent);

    sort_gather_mm_kernel<<<NBINS, 512, 0, stream>>>(
        src16, dst_feat, counts, ent, out);
}